// Round 1
// baseline (501.173 us; speedup 1.0000x reference)
//
#include <hip/hip_runtime.h>
#include <hip/hip_bf16.h>

// CrossWinAttention fp32 baseline.
// Shapes: B=2, N=6, X=Y=W1=W2=8, D=128, HEADS=4, DIM_HEAD=32
// L = 64 windows, Q = 384 tokens/window, TOK = 49152 total tokens.
//
// Pipeline:
//   1) ln_proj_kernel x3 : fold + LayerNorm + (128x128) projection -> qp/kp/vp
//   2) attn_kernel       : per (b,l,head) online-softmax attention -> ao
//   3) mean_kernel       : mean over N (linear, commutes with final proj)
//   4) proj_skip_kernel  : (8192x128)@(128x128) + bias + skip -> out

constexpr int BB  = 2;
constexpr int LL  = 64;    // X*Y
constexpr int QQ  = 384;   // N*W1*W2
constexpr int TOK = BB * LL * QQ;  // 49152
constexpr float EPSF = 1e-5f;

// ---------------------------------------------------------------------------
// Kernel 1: fold + LayerNorm + projection (one tensor per launch)
// grid.x = TOK/32, block = 256. LDS: W 64KB + X 16KB = 80KB -> 2 blocks/CU.
// ---------------------------------------------------------------------------
__global__ __launch_bounds__(256) void ln_proj_kernel(
    const float* __restrict__ in, const float* __restrict__ gamma,
    const float* __restrict__ beta, const float* __restrict__ W,
    const float* __restrict__ bias, float* __restrict__ out)
{
  __shared__ float4 Wl[128 * 32];  // W[d][j] as float4 over j
  __shared__ float4 Xl[32 * 32];   // xn[t][d] as float4 over d
  const int tid = threadIdx.x;

  const float4* W4 = (const float4*)W;
#pragma unroll
  for (int i = 0; i < 16; ++i) Wl[i * 256 + tid] = W4[i * 256 + tid];

  // ---- LayerNorm: one wave per token, 8 tokens per wave ----
  const int wave = tid >> 6, lane = tid & 63;
  const int tile0 = blockIdx.x * 32;
  const float2 gg = ((const float2*)gamma)[lane];
  const float2 be = ((const float2*)beta)[lane];
  for (int s = 0; s < 8; ++s) {
    const int tl = wave * 8 + s;
    const int tg = tile0 + tl;
    // token tg -> (b, l, t) ; t = n*64 + w
    const int b   = tg / (LL * QQ);
    const int rem = tg - b * (LL * QQ);
    const int l   = rem / QQ;
    const int t   = rem - l * QQ;
    const int n   = t >> 6;
    const int w   = t & 63;
    // input flat: (((b*6+n)*64 + l)*64 + w)*128 + d
    const float* src = in + (((size_t)((b * 6 + n) * 64 + l) * 64 + w) << 7);
    const float2 v = ((const float2*)src)[lane];
    float sum = v.x + v.y;
    float sq  = v.x * v.x + v.y * v.y;
#pragma unroll
    for (int o = 32; o >= 1; o >>= 1) {
      sum += __shfl_xor(sum, o);
      sq  += __shfl_xor(sq, o);
    }
    const float mean = sum * (1.f / 128.f);
    const float var  = sq * (1.f / 128.f) - mean * mean;
    const float rstd = rsqrtf(var + EPSF);
    float2 xn;
    xn.x = (v.x - mean) * rstd * gg.x + be.x;
    xn.y = (v.y - mean) * rstd * gg.y + be.y;
    ((float2*)&Xl[tl * 32])[lane] = xn;
  }
  __syncthreads();

  // ---- GEMM: thread = 4 tokens x 4 cols ----
  const int jg  = tid & 31;   // col group: cols jg*4 .. jg*4+3
  const int tg4 = tid >> 5;   // token group: tokens tg4*4 .. +3
  float acc[4][4];
#pragma unroll
  for (int a = 0; a < 4; ++a)
#pragma unroll
    for (int c = 0; c < 4; ++c) acc[a][c] = 0.f;

  for (int d4 = 0; d4 < 32; ++d4) {
    float4 wv[4], xv[4];
#pragma unroll
    for (int dd = 0; dd < 4; ++dd) wv[dd] = Wl[(d4 * 4 + dd) * 32 + jg];
#pragma unroll
    for (int tt = 0; tt < 4; ++tt) xv[tt] = Xl[(tg4 * 4 + tt) * 32 + d4];
#pragma unroll
    for (int tt = 0; tt < 4; ++tt) {
      const float4 x = xv[tt];
#define FMA4(xc, wvd)                 \
      acc[tt][0] += (xc) * (wvd).x;   \
      acc[tt][1] += (xc) * (wvd).y;   \
      acc[tt][2] += (xc) * (wvd).z;   \
      acc[tt][3] += (xc) * (wvd).w;
      FMA4(x.x, wv[0]) FMA4(x.y, wv[1]) FMA4(x.z, wv[2]) FMA4(x.w, wv[3])
#undef FMA4
    }
  }

  const float4 bv = ((const float4*)bias)[jg];
  float4* out4 = (float4*)out;
#pragma unroll
  for (int tt = 0; tt < 4; ++tt) {
    const int row = tile0 + tg4 * 4 + tt;
    float4 o;
    o.x = acc[tt][0] + bv.x;
    o.y = acc[tt][1] + bv.y;
    o.z = acc[tt][2] + bv.z;
    o.w = acc[tt][3] + bv.w;
    out4[(size_t)row * 32 + jg] = o;
  }
}

// ---------------------------------------------------------------------------
// Kernel 2: attention, one block per (b,l,head). 384 threads = 1 q-row each.
// K/V streamed through LDS in 32-row chunks; online softmax in registers.
// ---------------------------------------------------------------------------
__global__ __launch_bounds__(384) void attn_kernel(
    const float* __restrict__ qp, const float* __restrict__ kp,
    const float* __restrict__ vp, float* __restrict__ ao)
{
  __shared__ float Ks[32 * 32];
  __shared__ float Vs[32 * 32];
  const int tid = threadIdx.x;
  const int bid = blockIdx.x;
  const int h  = bid & 3;
  const int bl = bid >> 2;  // b*64 + l
  const size_t base = (size_t)bl * QQ * 128 + (size_t)h * 32;
  const float* kb = kp + base;
  const float* vb = vp + base;

  const float scale = 0.17677669529663687f;  // 32^-0.5
  float4 qv[8];
  {
    const float4* q4 = (const float4*)(qp + base + (size_t)tid * 128);
#pragma unroll
    for (int i = 0; i < 8; ++i) {
      qv[i] = q4[i];
      qv[i].x *= scale; qv[i].y *= scale; qv[i].z *= scale; qv[i].w *= scale;
    }
  }

  float m = -1e30f, se = 0.f;
  float4 acc[8];
#pragma unroll
  for (int i = 0; i < 8; ++i) acc[i] = make_float4(0.f, 0.f, 0.f, 0.f);

  for (int c = 0; c < 12; ++c) {
    __syncthreads();
    if (tid < 256) {
      const int row = tid >> 3, d4 = tid & 7;
      ((float4*)Ks)[tid] = ((const float4*)(kb + (size_t)(c * 32 + row) * 128))[d4];
      ((float4*)Vs)[tid] = ((const float4*)(vb + (size_t)(c * 32 + row) * 128))[d4];
    }
    __syncthreads();

    // scores for this chunk (q pre-scaled)
    float s[32];
    const float4* K4 = (const float4*)Ks;
#pragma unroll
    for (int kk = 0; kk < 32; ++kk) {
      float a = 0.f;
#pragma unroll
      for (int i = 0; i < 8; ++i) {
        const float4 k4 = K4[kk * 8 + i];
        a += qv[i].x * k4.x + qv[i].y * k4.y + qv[i].z * k4.z + qv[i].w * k4.w;
      }
      s[kk] = a;
    }

    float cm = s[0];
#pragma unroll
    for (int kk = 1; kk < 32; ++kk) cm = fmaxf(cm, s[kk]);
    const float nm = fmaxf(m, cm);
    const float corr = __expf(m - nm);  // first chunk: exp(-1e30) = 0, no NaN
    se *= corr;
#pragma unroll
    for (int i = 0; i < 8; ++i) {
      acc[i].x *= corr; acc[i].y *= corr; acc[i].z *= corr; acc[i].w *= corr;
    }

    const float4* V4 = (const float4*)Vs;
#pragma unroll
    for (int kk = 0; kk < 32; ++kk) {
      const float p = __expf(s[kk] - nm);
      se += p;
#pragma unroll
      for (int i = 0; i < 8; ++i) {
        const float4 vv = V4[kk * 8 + i];
        acc[i].x += p * vv.x; acc[i].y += p * vv.y;
        acc[i].z += p * vv.z; acc[i].w += p * vv.w;
      }
    }
    m = nm;
  }

  const float inv = 1.f / se;
  float4* o4 = (float4*)(ao + base + (size_t)tid * 128);
#pragma unroll
  for (int i = 0; i < 8; ++i) {
    float4 o;
    o.x = acc[i].x * inv; o.y = acc[i].y * inv;
    o.z = acc[i].z * inv; o.w = acc[i].w * inv;
    o4[i] = o;
  }
}

// ---------------------------------------------------------------------------
// Kernel 3: mean over N (6 views). abar[(bl*64+w)*128+d] = mean_n ao[bl][n*64+w][d]
// ---------------------------------------------------------------------------
__global__ __launch_bounds__(256) void mean_kernel(
    const float* __restrict__ ao, float* __restrict__ abar)
{
  const int gid = blockIdx.x * 256 + threadIdx.x;  // 0..262143 (float4 units)
  const int d4 = gid & 31;
  const int rw = gid >> 5;   // bl*64 + w
  const int w  = rw & 63;
  const int bl = rw >> 6;
  const float4* a4 = (const float4*)ao;
  const size_t rbase = ((size_t)bl * 384 + w) * 32 + d4;
  float4 s = make_float4(0.f, 0.f, 0.f, 0.f);
#pragma unroll
  for (int n = 0; n < 6; ++n) {
    const float4 vv = a4[rbase + (size_t)n * 64 * 32];
    s.x += vv.x; s.y += vv.y; s.z += vv.z; s.w += vv.w;
  }
  const float inv6 = 1.f / 6.f;
  float4 o;
  o.x = s.x * inv6; o.y = s.y * inv6; o.z = s.z * inv6; o.w = s.w * inv6;
  ((float4*)abar)[gid] = o;
}

// ---------------------------------------------------------------------------
// Kernel 4: final projection + bias + skip. 8192 rows; out row == abar row.
// ---------------------------------------------------------------------------
__global__ __launch_bounds__(256) void proj_skip_kernel(
    const float* __restrict__ Xin, const float* __restrict__ W,
    const float* __restrict__ bias, const float* __restrict__ skip,
    float* __restrict__ out)
{
  __shared__ float4 Wl[128 * 32];
  __shared__ float4 Xl[32 * 32];
  const int tid = threadIdx.x;
  const float4* W4 = (const float4*)W;
#pragma unroll
  for (int i = 0; i < 16; ++i) Wl[i * 256 + tid] = W4[i * 256 + tid];
  const int tile0 = blockIdx.x * 32;
  const float4* X4 = (const float4*)Xin;
#pragma unroll
  for (int i = 0; i < 4; ++i)
    Xl[i * 256 + tid] = X4[(size_t)tile0 * 32 + i * 256 + tid];
  __syncthreads();

  const int jg  = tid & 31;
  const int tg4 = tid >> 5;
  float acc[4][4];
#pragma unroll
  for (int a = 0; a < 4; ++a)
#pragma unroll
    for (int c = 0; c < 4; ++c) acc[a][c] = 0.f;

  for (int d4 = 0; d4 < 32; ++d4) {
    float4 wv[4], xv[4];
#pragma unroll
    for (int dd = 0; dd < 4; ++dd) wv[dd] = Wl[(d4 * 4 + dd) * 32 + jg];
#pragma unroll
    for (int tt = 0; tt < 4; ++tt) xv[tt] = Xl[(tg4 * 4 + tt) * 32 + d4];
#pragma unroll
    for (int tt = 0; tt < 4; ++tt) {
      const float4 x = xv[tt];
#define FMA4(xc, wvd)                 \
      acc[tt][0] += (xc) * (wvd).x;   \
      acc[tt][1] += (xc) * (wvd).y;   \
      acc[tt][2] += (xc) * (wvd).z;   \
      acc[tt][3] += (xc) * (wvd).w;
      FMA4(x.x, wv[0]) FMA4(x.y, wv[1]) FMA4(x.z, wv[2]) FMA4(x.w, wv[3])
#undef FMA4
    }
  }

  const float4 bv = ((const float4*)bias)[jg];
  float4* out4 = (float4*)out;
  const float4* sk4 = (const float4*)skip;
#pragma unroll
  for (int tt = 0; tt < 4; ++tt) {
    const int row = tile0 + tg4 * 4 + tt;
    const float4 sk = sk4[(size_t)row * 32 + jg];
    float4 o;
    o.x = acc[tt][0] + bv.x + sk.x;
    o.y = acc[tt][1] + bv.y + sk.y;
    o.z = acc[tt][2] + bv.z + sk.z;
    o.w = acc[tt][3] + bv.w + sk.w;
    out4[(size_t)row * 32 + jg] = o;
  }
}

// ---------------------------------------------------------------------------
extern "C" void kernel_launch(void* const* d_in, const int* in_sizes, int n_in,
                              void* d_out, int out_size, void* d_ws, size_t ws_size,
                              hipStream_t stream)
{
  const float* q     = (const float*)d_in[0];
  const float* k     = (const float*)d_in[1];
  const float* v     = (const float*)d_in[2];
  const float* skip  = (const float*)d_in[3];
  const float* lnq_g = (const float*)d_in[4];
  const float* lnq_b = (const float*)d_in[5];
  const float* lnk_g = (const float*)d_in[6];
  const float* lnk_b = (const float*)d_in[7];
  const float* lnv_g = (const float*)d_in[8];
  const float* lnv_b = (const float*)d_in[9];
  const float* wq = (const float*)d_in[10];
  const float* bq = (const float*)d_in[11];
  const float* wk = (const float*)d_in[12];
  const float* bk = (const float*)d_in[13];
  const float* wv = (const float*)d_in[14];
  const float* bv = (const float*)d_in[15];
  const float* wp = (const float*)d_in[16];
  const float* bp = (const float*)d_in[17];
  float* out = (float*)d_out;

  float* ws = (float*)d_ws;
  const size_t PROJ = (size_t)TOK * 128;  // 6,291,456 floats per buffer
  float* qp = ws;
  float* kp = ws + PROJ;
  float* vp = ws + 2 * PROJ;
  float* ao = ws + 3 * PROJ;
  float* abar = qp;  // qp dead after attention; reuse (8192*128 floats)

  ln_proj_kernel<<<TOK / 32, 256, 0, stream>>>(q, lnq_g, lnq_b, wq, bq, qp);
  ln_proj_kernel<<<TOK / 32, 256, 0, stream>>>(k, lnk_g, lnk_b, wk, bk, kp);
  ln_proj_kernel<<<TOK / 32, 256, 0, stream>>>(v, lnv_g, lnv_b, wv, bv, vp);
  attn_kernel<<<BB * LL * 4, 384, 0, stream>>>(qp, kp, vp, ao);
  mean_kernel<<<1024, 256, 0, stream>>>(ao, abar);
  proj_skip_kernel<<<8192 / 32, 256, 0, stream>>>(abar, wp, bp, skip, out);
}

// Round 2
// 273.889 us; speedup vs baseline: 1.8298x; 1.8298x over previous
//
#include <hip/hip_runtime.h>
#include <hip/hip_bf16.h>

// CrossWinAttention — bf16 MFMA pipeline.
// Shapes: B=2, N=6, X=Y=W1=W2=8, D=128, HEADS=4, DIM_HEAD=32
// L=64 windows, Q=384 tokens/window, TOK=49152.
//
//   0) transpose_w_kernel : wq/wk/wv (f32, [d][j]) -> wt (bf16, [j][d])
//   1) ln_proj_mfma x3    : fold + LayerNorm(f32) + MFMA projection -> bf16 qp/kp/vp
//                           (q gets DIM_HEAD^-0.5 folded in)
//   2) attn_mfma_kernel   : per (b,l,head), online softmax, QK^T/PV via
//                           mfma_f32_16x16x32_bf16; row-sums via ones-MFMA -> f32 ao
//   3) mean_kernel        : mean over N (commutes with final projection)
//   4) proj_skip_kernel   : f32 (8192x128)@(128x128) + bias + skip -> out

typedef __attribute__((ext_vector_type(8))) __bf16 bf16x8;
typedef __attribute__((ext_vector_type(4))) float f32x4;
typedef __attribute__((ext_vector_type(4))) unsigned short u16x4;

constexpr int BB  = 2;
constexpr int LL  = 64;
constexpr int QQ  = 384;
constexpr int TOK = BB * LL * QQ;  // 49152
constexpr float EPSF = 1e-5f;
constexpr float QSCALE = 0.17677669529663687f;  // 32^-0.5

__device__ __forceinline__ unsigned short f2bf(float x) {
  union { float f; unsigned u; } v; v.f = x;
  const unsigned r = v.u + 0x7FFFu + ((v.u >> 16) & 1u);  // RNE
  return (unsigned short)(r >> 16);
}

// ---------------------------------------------------------------------------
// Kernel 0: W transpose + bf16 cast (wt[j][d] so B-frags are contiguous-k).
// ---------------------------------------------------------------------------
__global__ __launch_bounds__(256) void transpose_w_kernel(
    const float* __restrict__ wq, const float* __restrict__ wk,
    const float* __restrict__ wv, unsigned short* __restrict__ tq,
    unsigned short* __restrict__ tk, unsigned short* __restrict__ tv)
{
  const int e = blockIdx.x * 256 + threadIdx.x;  // 0..16383
  const int d = e >> 7, j = e & 127;
  const int o = j * 128 + d;
  tq[o] = f2bf(wq[e]);
  tk[o] = f2bf(wk[e]);
  tv[o] = f2bf(wv[e]);
}

// ---------------------------------------------------------------------------
// Kernel 1: fold + LayerNorm (f32) + MFMA projection -> bf16 out.
// Block: 256 threads / 4 waves, 64 tokens. Xs swizzled: byte ^= (row&7)<<4.
// ---------------------------------------------------------------------------
__global__ __launch_bounds__(256) void ln_proj_mfma(
    const float* __restrict__ in, const float* __restrict__ gamma,
    const float* __restrict__ beta, const unsigned short* __restrict__ wt,
    const float* __restrict__ bias, const float scale,
    unsigned short* __restrict__ out)
{
  __shared__ __align__(16) unsigned short Xs[64 * 128];
  const int tid = threadIdx.x, wave = tid >> 6, lane = tid & 63;
  const int tile0 = blockIdx.x * 64;
  const float2 gg = ((const float2*)gamma)[lane];
  const float2 be = ((const float2*)beta)[lane];
  for (int s = 0; s < 16; ++s) {
    const int tl = wave * 16 + s;
    const int tg = tile0 + tl;
    const int b = tg / 24576; const int rem = tg - b * 24576;
    const int l = rem / 384;  const int t = rem - l * 384;
    const int n = t >> 6, w = t & 63;
    const float* src = in + (((size_t)((b * 6 + n) * 64 + l) * 64 + w) << 7);
    const float2 v = ((const float2*)src)[lane];
    float sum = v.x + v.y, sq = v.x * v.x + v.y * v.y;
#pragma unroll
    for (int o = 32; o >= 1; o >>= 1) { sum += __shfl_xor(sum, o); sq += __shfl_xor(sq, o); }
    const float mean = sum * (1.f / 128.f);
    const float var = sq * (1.f / 128.f) - mean * mean;
    const float rstd = rsqrtf(var + EPSF);
    const unsigned short b0 = f2bf((v.x - mean) * rstd * gg.x + be.x);
    const unsigned short b1 = f2bf((v.y - mean) * rstd * gg.y + be.y);
    const unsigned pk = (unsigned)b0 | ((unsigned)b1 << 16);
    *(unsigned*)&Xs[(tl * 128 + lane * 2) ^ ((tl & 7) << 3)] = pk;
  }
  __syncthreads();

  const int lr = lane & 15, lg = lane >> 4;
  f32x4 accn[8];
#pragma unroll
  for (int i = 0; i < 8; ++i) accn[i] = (f32x4)0.f;
#pragma unroll
  for (int ks = 0; ks < 4; ++ks) {
    const bf16x8 xa = *(const bf16x8*)&Xs[((wave * 16 + lr) * 128 + ks * 32 + lg * 8) ^ ((lr & 7) << 3)];
#pragma unroll
    for (int nt = 0; nt < 8; ++nt) {
      const bf16x8 wb = *(const bf16x8*)(wt + (size_t)(nt * 16 + lr) * 128 + ks * 32 + lg * 8);
      accn[nt] = __builtin_amdgcn_mfma_f32_16x16x32_bf16(xa, wb, accn[nt], 0, 0, 0);
    }
  }
#pragma unroll
  for (int nt = 0; nt < 8; ++nt) {
    const float bv = bias[nt * 16 + lr];
#pragma unroll
    for (int r = 0; r < 4; ++r) {
      const int row = tile0 + wave * 16 + lg * 4 + r;
      out[(size_t)row * 128 + nt * 16 + lr] = f2bf((accn[nt][r] + bv) * scale);
    }
  }
}

// ---------------------------------------------------------------------------
// Kernel 2: attention. Block = (b,l,h), 256 threads / 4 waves, 96 q-rows/wave.
// KV chunk = 32. Q/K frags straight from global (contiguous-k); V via small
// LDS transpose; P via per-wave swizzled LDS; row-sum via ones-MFMA.
// ---------------------------------------------------------------------------
__global__ __launch_bounds__(256) void attn_mfma_kernel(
    const unsigned short* __restrict__ qp, const unsigned short* __restrict__ kp,
    const unsigned short* __restrict__ vp, float* __restrict__ ao)
{
  __shared__ __align__(16) unsigned short Vt[1024];     // [d][k] 32x32, swizzled
  __shared__ __align__(16) unsigned short Pl[4][512];   // per-wave [q][k] 16x32, swizzled
  const int tid = threadIdx.x, wave = tid >> 6, lane = tid & 63;
  const int lr = lane & 15, lg = lane >> 4;
  const int h = blockIdx.x & 3, bl = blockIdx.x >> 2;
  const size_t base = (size_t)bl * (QQ * 128) + h * 32;
  const int qbase = wave * 96;

  bf16x8 qf[6];
#pragma unroll
  for (int t = 0; t < 6; ++t)
    qf[t] = *(const bf16x8*)(qp + base + (size_t)(qbase + t * 16 + lr) * 128 + lg * 8);

  f32x4 acc[6][2]; f32x4 sea[6]; float mrow[6];
#pragma unroll
  for (int t = 0; t < 6; ++t) {
    acc[t][0] = (f32x4)0.f; acc[t][1] = (f32x4)0.f;
    sea[t] = (f32x4)0.f; mrow[t] = -1e30f;
  }
  bf16x8 ones;
#pragma unroll
  for (int i = 0; i < 8; ++i) ones[i] = (__bf16)1.0f;
  const f32x4 zf = (f32x4)0.f;

  for (int c = 0; c < 12; ++c) {
    __syncthreads();
    {  // cooperative V-transpose into LDS (bf16, swizzled rows)
      const int k = tid >> 3, d0 = (tid & 7) * 4;
      const u16x4 vv = *(const u16x4*)(vp + base + (size_t)(c * 32 + k) * 128 + d0);
#pragma unroll
      for (int i = 0; i < 4; ++i) {
        const int d = d0 + i;
        Vt[(d * 32 + k) ^ ((d & 7) << 3)] = vv[i];
      }
    }
    __syncthreads();
    const bf16x8 kf0 = *(const bf16x8*)(kp + base + (size_t)(c * 32 + lr) * 128 + lg * 8);
    const bf16x8 kf1 = *(const bf16x8*)(kp + base + (size_t)(c * 32 + 16 + lr) * 128 + lg * 8);
    const bf16x8 vf0 = *(const bf16x8*)&Vt[(lr * 32 + lg * 8) ^ ((lr & 7) << 3)];
    const bf16x8 vf1 = *(const bf16x8*)&Vt[((16 + lr) * 32 + lg * 8) ^ ((lr & 7) << 3)];

#pragma unroll
    for (int t = 0; t < 6; ++t) {
      f32x4 s0 = __builtin_amdgcn_mfma_f32_16x16x32_bf16(qf[t], kf0, zf, 0, 0, 0);
      f32x4 s1 = __builtin_amdgcn_mfma_f32_16x16x32_bf16(qf[t], kf1, zf, 0, 0, 0);
      // per-16-row-tile max (safe for softmax stability; scores |s| << 88)
      float cm = fmaxf(fmaxf(fmaxf(s0[0], s0[1]), fmaxf(s0[2], s0[3])),
                       fmaxf(fmaxf(s1[0], s1[1]), fmaxf(s1[2], s1[3])));
      cm = fmaxf(cm, __shfl_xor(cm, 1));
      cm = fmaxf(cm, __shfl_xor(cm, 2));
      cm = fmaxf(cm, __shfl_xor(cm, 4));
      cm = fmaxf(cm, __shfl_xor(cm, 8));
      const float mo = mrow[t];
      const float mn = fmaxf(mo, cm);
      const float corr = __expf(mo - mn);  // chunk 0: exp(-1e30) = 0
      mrow[t] = mn;
#pragma unroll
      for (int r = 0; r < 4; ++r) {
        acc[t][0][r] *= corr; acc[t][1][r] *= corr; sea[t][r] *= corr;
      }
#pragma unroll
      for (int r = 0; r < 4; ++r) {
        const float p0 = __expf(s0[r] - mn), p1 = __expf(s1[r] - mn);
        const int q = lg * 4 + r;
        Pl[wave][(q * 32 + lr) ^ ((q & 7) << 3)] = f2bf(p0);
        Pl[wave][(q * 32 + 16 + lr) ^ ((q & 7) << 3)] = f2bf(p1);
      }
      __builtin_amdgcn_sched_barrier(0);  // keep pa-load after P-stores (rule #18)
      const bf16x8 pa = *(const bf16x8*)&Pl[wave][(lr * 32 + lg * 8) ^ ((lr & 7) << 3)];
      acc[t][0] = __builtin_amdgcn_mfma_f32_16x16x32_bf16(pa, vf0, acc[t][0], 0, 0, 0);
      acc[t][1] = __builtin_amdgcn_mfma_f32_16x16x32_bf16(pa, vf1, acc[t][1], 0, 0, 0);
      sea[t]    = __builtin_amdgcn_mfma_f32_16x16x32_bf16(pa, ones, sea[t], 0, 0, 0);
      __builtin_amdgcn_sched_barrier(0);  // keep next-iter P-stores after pa-load
    }
  }

#pragma unroll
  for (int t = 0; t < 6; ++t) {
#pragma unroll
    for (int r = 0; r < 4; ++r) {
      const float inv = 1.f / sea[t][r];
      const int row = qbase + t * 16 + lg * 4 + r;
      float* orow = ao + (size_t)(bl * QQ + row) * 128 + h * 32;
      orow[lr]      = acc[t][0][r] * inv;
      orow[16 + lr] = acc[t][1][r] * inv;
    }
  }
}

// ---------------------------------------------------------------------------
// Kernel 3: mean over N (6 views), f32.
// ---------------------------------------------------------------------------
__global__ __launch_bounds__(256) void mean_kernel(
    const float* __restrict__ ao, float* __restrict__ abar)
{
  const int gid = blockIdx.x * 256 + threadIdx.x;  // float4 units
  const int d4 = gid & 31;
  const int rw = gid >> 5;
  const int w  = rw & 63;
  const int bl = rw >> 6;
  const float4* a4 = (const float4*)ao;
  const size_t rbase = ((size_t)bl * 384 + w) * 32 + d4;
  float4 s = make_float4(0.f, 0.f, 0.f, 0.f);
#pragma unroll
  for (int n = 0; n < 6; ++n) {
    const float4 vv = a4[rbase + (size_t)n * 64 * 32];
    s.x += vv.x; s.y += vv.y; s.z += vv.z; s.w += vv.w;
  }
  const float inv6 = 1.f / 6.f;
  float4 o;
  o.x = s.x * inv6; o.y = s.y * inv6; o.z = s.z * inv6; o.w = s.w * inv6;
  ((float4*)abar)[gid] = o;
}

// ---------------------------------------------------------------------------
// Kernel 4: final projection + bias + skip (f32 LDS GEMM, unchanged).
// ---------------------------------------------------------------------------
__global__ __launch_bounds__(256) void proj_skip_kernel(
    const float* __restrict__ Xin, const float* __restrict__ W,
    const float* __restrict__ bias, const float* __restrict__ skip,
    float* __restrict__ out)
{
  __shared__ float4 Wl[128 * 32];
  __shared__ float4 Xl[32 * 32];
  const int tid = threadIdx.x;
  const float4* W4 = (const float4*)W;
#pragma unroll
  for (int i = 0; i < 16; ++i) Wl[i * 256 + tid] = W4[i * 256 + tid];
  const int tile0 = blockIdx.x * 32;
  const float4* X4 = (const float4*)Xin;
#pragma unroll
  for (int i = 0; i < 4; ++i)
    Xl[i * 256 + tid] = X4[(size_t)tile0 * 32 + i * 256 + tid];
  __syncthreads();

  const int jg  = tid & 31;
  const int tg4 = tid >> 5;
  float acc[4][4];
#pragma unroll
  for (int a = 0; a < 4; ++a)
#pragma unroll
    for (int c = 0; c < 4; ++c) acc[a][c] = 0.f;

  for (int d4 = 0; d4 < 32; ++d4) {
    float4 wv[4], xv[4];
#pragma unroll
    for (int dd = 0; dd < 4; ++dd) wv[dd] = Wl[(d4 * 4 + dd) * 32 + jg];
#pragma unroll
    for (int tt = 0; tt < 4; ++tt) xv[tt] = Xl[(tg4 * 4 + tt) * 32 + d4];
#pragma unroll
    for (int tt = 0; tt < 4; ++tt) {
      const float4 x = xv[tt];
#define FMA4(xc, wvd)                 \
      acc[tt][0] += (xc) * (wvd).x;   \
      acc[tt][1] += (xc) * (wvd).y;   \
      acc[tt][2] += (xc) * (wvd).z;   \
      acc[tt][3] += (xc) * (wvd).w;
      FMA4(x.x, wv[0]) FMA4(x.y, wv[1]) FMA4(x.z, wv[2]) FMA4(x.w, wv[3])
#undef FMA4
    }
  }

  const float4 bv = ((const float4*)bias)[jg];
  float4* out4 = (float4*)out;
  const float4* sk4 = (const float4*)skip;
#pragma unroll
  for (int tt = 0; tt < 4; ++tt) {
    const int row = tile0 + tg4 * 4 + tt;
    const float4 sk = sk4[(size_t)row * 32 + jg];
    float4 o;
    o.x = acc[tt][0] + bv.x + sk.x;
    o.y = acc[tt][1] + bv.y + sk.y;
    o.z = acc[tt][2] + bv.z + sk.z;
    o.w = acc[tt][3] + bv.w + sk.w;
    out4[(size_t)row * 32 + jg] = o;
  }
}

// ---------------------------------------------------------------------------
extern "C" void kernel_launch(void* const* d_in, const int* in_sizes, int n_in,
                              void* d_out, int out_size, void* d_ws, size_t ws_size,
                              hipStream_t stream)
{
  const float* q     = (const float*)d_in[0];
  const float* k     = (const float*)d_in[1];
  const float* v     = (const float*)d_in[2];
  const float* skip  = (const float*)d_in[3];
  const float* lnq_g = (const float*)d_in[4];
  const float* lnq_b = (const float*)d_in[5];
  const float* lnk_g = (const float*)d_in[6];
  const float* lnk_b = (const float*)d_in[7];
  const float* lnv_g = (const float*)d_in[8];
  const float* lnv_b = (const float*)d_in[9];
  const float* wq = (const float*)d_in[10];
  const float* bq = (const float*)d_in[11];
  const float* wk = (const float*)d_in[12];
  const float* bk = (const float*)d_in[13];
  const float* wv = (const float*)d_in[14];
  const float* bv = (const float*)d_in[15];
  const float* wp = (const float*)d_in[16];
  const float* bp = (const float*)d_in[17];
  float* out = (float*)d_out;

  // workspace carve (bytes): qp/kp/vp bf16 12.58MB each, ao f32 25.2MB,
  // abar f32 4.2MB, wt 3x32KB. Total ~67.3MB.
  const size_t PROJ = (size_t)TOK * 128;  // elements
  unsigned short* qp = (unsigned short*)d_ws;
  unsigned short* kp = qp + PROJ;
  unsigned short* vp = kp + PROJ;
  float* ao   = (float*)(vp + PROJ);
  float* abar = ao + PROJ;
  unsigned short* wtq = (unsigned short*)(abar + (size_t)8192 * 128);
  unsigned short* wtk = wtq + 16384;
  unsigned short* wtv = wtk + 16384;

  transpose_w_kernel<<<64, 256, 0, stream>>>(wq, wk, wv, wtq, wtk, wtv);
  ln_proj_mfma<<<TOK / 64, 256, 0, stream>>>(q, lnq_g, lnq_b, wtq, bq, QSCALE, qp);
  ln_proj_mfma<<<TOK / 64, 256, 0, stream>>>(k, lnk_g, lnk_b, wtk, bk, 1.0f, kp);
  ln_proj_mfma<<<TOK / 64, 256, 0, stream>>>(v, lnv_g, lnv_b, wtv, bv, 1.0f, vp);
  attn_mfma_kernel<<<BB * LL * 4, 256, 0, stream>>>(qp, kp, vp, ao);
  mean_kernel<<<1024, 256, 0, stream>>>(ao, abar);
  proj_skip_kernel<<<8192 / 32, 256, 0, stream>>>(abar, wp, bp, skip, out);
}

// Round 3
// 232.606 us; speedup vs baseline: 2.1546x; 1.1775x over previous
//
#include <hip/hip_runtime.h>
#include <hip/hip_bf16.h>

// CrossWinAttention — bf16 MFMA pipeline, round 3.
// B=2, N=6, X=Y=W1=W2=8, D=128, HEADS=4, DIM_HEAD=32; L=64, Q=384, TOK=49152.
//
//   0) transpose_w_kernel : wq/wk/wv (f32 [d][j]) -> bf16 [j][d]
//   1) ln_proj_all        : all three LN+proj in ONE launch (2304 blocks)
//   2) attn_mfma_kernel   : (b,l,h,qhalf) blocks; V staged once (no inner
//                           barriers); online softmax; ones-MFMA row sums
//   3) proj_skip_mean     : mean over N fused into final GEMM + bias + skip

typedef __attribute__((ext_vector_type(8))) __bf16 bf16x8;
typedef __attribute__((ext_vector_type(4))) float f32x4;
typedef __attribute__((ext_vector_type(4))) unsigned short u16x4;

constexpr int BB  = 2;
constexpr int LL  = 64;
constexpr int QQ  = 384;
constexpr int TOK = BB * LL * QQ;  // 49152
constexpr float EPSF = 1e-5f;
constexpr float QSCALE = 0.17677669529663687f;  // 32^-0.5

__device__ __forceinline__ unsigned short f2bf(float x) {
  union { float f; unsigned u; } v; v.f = x;
  const unsigned r = v.u + 0x7FFFu + ((v.u >> 16) & 1u);  // RNE
  return (unsigned short)(r >> 16);
}
__device__ __forceinline__ unsigned short f2bf_trunc(float x) {
  union { float f; unsigned u; } v; v.f = x;
  return (unsigned short)(v.u >> 16);
}

// ---------------------------------------------------------------------------
// Kernel 0: W transpose + bf16 cast.
// ---------------------------------------------------------------------------
__global__ __launch_bounds__(256) void transpose_w_kernel(
    const float* __restrict__ wq, const float* __restrict__ wk,
    const float* __restrict__ wv, unsigned short* __restrict__ tq,
    unsigned short* __restrict__ tk, unsigned short* __restrict__ tv)
{
  const int e = blockIdx.x * 256 + threadIdx.x;  // 0..16383
  const int d = e >> 7, j = e & 127;
  const int o = j * 128 + d;
  tq[o] = f2bf(wq[e]);
  tk[o] = f2bf(wk[e]);
  tv[o] = f2bf(wv[e]);
}

// ---------------------------------------------------------------------------
// Kernel 1: fused q/k/v LN + MFMA projection. 2304 blocks; seg = which tensor.
// LN: 4 tokens in parallel per wave (16 lanes/token), 4 iterations.
// ---------------------------------------------------------------------------
__global__ __launch_bounds__(256) void ln_proj_all(
    const float* __restrict__ inq, const float* __restrict__ ink,
    const float* __restrict__ inv,
    const float* __restrict__ gq, const float* __restrict__ bq,
    const float* __restrict__ gk, const float* __restrict__ bk,
    const float* __restrict__ gv, const float* __restrict__ bv,
    const unsigned short* __restrict__ wtq, const unsigned short* __restrict__ wtk,
    const unsigned short* __restrict__ wtv,
    const float* __restrict__ biq, const float* __restrict__ bik,
    const float* __restrict__ biv,
    unsigned short* __restrict__ oq, unsigned short* __restrict__ ok,
    unsigned short* __restrict__ ov)
{
  __shared__ __align__(16) unsigned short Xs[64 * 128];
  const int bid = blockIdx.x;
  const int seg = (bid >= 1536) ? 2 : (bid >= 768 ? 1 : 0);
  const float* in    = (seg == 0) ? inq : (seg == 1) ? ink : inv;
  const float* gamma = (seg == 0) ? gq  : (seg == 1) ? gk  : gv;
  const float* beta  = (seg == 0) ? bq  : (seg == 1) ? bk  : bv;
  const unsigned short* wt = (seg == 0) ? wtq : (seg == 1) ? wtk : wtv;
  const float* bias  = (seg == 0) ? biq : (seg == 1) ? bik : biv;
  unsigned short* out = (seg == 0) ? oq : (seg == 1) ? ok : ov;
  const float scale  = (seg == 0) ? QSCALE : 1.0f;

  const int tid = threadIdx.x, wave = tid >> 6, lane = tid & 63;
  const int tile0 = (bid - seg * 768) * 64;
  const int sl = lane & 15;          // 16 lanes per token
  const float4* g4 = (const float4*)gamma;
  const float4* be4 = (const float4*)beta;
  const float4 g0 = g4[sl * 2], g1 = g4[sl * 2 + 1];
  const float4 b0 = be4[sl * 2], b1 = be4[sl * 2 + 1];

  for (int it = 0; it < 4; ++it) {
    const int tl = wave * 16 + it * 4 + (lane >> 4);
    const int tg = tile0 + tl;
    const int b = tg / 24576; const int rem = tg - b * 24576;
    const int l = rem / 384;  const int t = rem - l * 384;
    const int n = t >> 6, w = t & 63;
    const float4* src = (const float4*)(in + (((size_t)((b * 6 + n) * 64 + l) * 64 + w) << 7));
    const float4 a = src[sl * 2], c = src[sl * 2 + 1];
    float sum = a.x + a.y + a.z + a.w + c.x + c.y + c.z + c.w;
    float sq = a.x * a.x + a.y * a.y + a.z * a.z + a.w * a.w
             + c.x * c.x + c.y * c.y + c.z * c.z + c.w * c.w;
#pragma unroll
    for (int o = 8; o >= 1; o >>= 1) { sum += __shfl_xor(sum, o); sq += __shfl_xor(sq, o); }
    const float mean = sum * (1.f / 128.f);
    const float var = sq * (1.f / 128.f) - mean * mean;
    const float rstd = rsqrtf(var + EPSF);
    bf16x8 xn;
    xn[0] = (__bf16)0; // placeholder, filled below
    unsigned short u[8];
    u[0] = f2bf((a.x - mean) * rstd * g0.x + b0.x);
    u[1] = f2bf((a.y - mean) * rstd * g0.y + b0.y);
    u[2] = f2bf((a.z - mean) * rstd * g0.z + b0.z);
    u[3] = f2bf((a.w - mean) * rstd * g0.w + b0.w);
    u[4] = f2bf((c.x - mean) * rstd * g1.x + b1.x);
    u[5] = f2bf((c.y - mean) * rstd * g1.y + b1.y);
    u[6] = f2bf((c.z - mean) * rstd * g1.z + b1.z);
    u[7] = f2bf((c.w - mean) * rstd * g1.w + b1.w);
    unsigned short* dst = &Xs[(tl * 128 + sl * 8) ^ ((tl & 7) << 3)];
#pragma unroll
    for (int j = 0; j < 8; ++j) dst[j] = u[j];
  }
  __syncthreads();

  const int lr = lane & 15, lg = lane >> 4;
  f32x4 accn[8];
#pragma unroll
  for (int i = 0; i < 8; ++i) accn[i] = (f32x4)0.f;
#pragma unroll
  for (int ks = 0; ks < 4; ++ks) {
    const bf16x8 xa = *(const bf16x8*)&Xs[((wave * 16 + lr) * 128 + ks * 32 + lg * 8) ^ ((lr & 7) << 3)];
#pragma unroll
    for (int nt = 0; nt < 8; ++nt) {
      const bf16x8 wb = *(const bf16x8*)(wt + (size_t)(nt * 16 + lr) * 128 + ks * 32 + lg * 8);
      accn[nt] = __builtin_amdgcn_mfma_f32_16x16x32_bf16(xa, wb, accn[nt], 0, 0, 0);
    }
  }
#pragma unroll
  for (int nt = 0; nt < 8; ++nt) {
    const float bv = bias[nt * 16 + lr];
#pragma unroll
    for (int r = 0; r < 4; ++r) {
      const int row = tile0 + wave * 16 + lg * 4 + r;
      out[(size_t)row * 128 + nt * 16 + lr] = f2bf((accn[nt][r] + bv) * scale);
    }
  }
}

// ---------------------------------------------------------------------------
// Kernel 2: attention. Block = (b,l,h,qhalf): 1024 blocks, 256 thr / 4 waves,
// 48 q-rows per wave. All of V (384x32) staged transposed+swizzled in LDS
// once -> no barriers in the chunk loop. Row sums via ones-MFMA.
// ---------------------------------------------------------------------------
__global__ __launch_bounds__(256) void attn_mfma_kernel(
    const unsigned short* __restrict__ qp, const unsigned short* __restrict__ kp,
    const unsigned short* __restrict__ vp, float* __restrict__ ao)
{
  __shared__ __align__(16) unsigned short Vt[32 * 384];   // [d][k], k-swizzled
  __shared__ __align__(16) unsigned short Pl[4][512];     // per-wave [q16][k32]
  const int tid = threadIdx.x, wave = tid >> 6, lane = tid & 63;
  const int lr = lane & 15, lg = lane >> 4;
  const int bid = blockIdx.x;
  const int qh = bid & 1, h = (bid >> 1) & 3, bl = bid >> 3;
  const size_t base = (size_t)bl * (QQ * 128) + h * 32;
  const int qbase = qh * 192 + wave * 48;

  // ---- stage all V transposed: Vt[d][k ^ ((d&7)<<3)] ----
#pragma unroll
  for (int i = 0; i < 12; ++i) {
    const int lin = i * 256 + tid;       // 0..3071
    const int k = lin >> 3, d0 = (lin & 7) * 4;
    const u16x4 vv = *(const u16x4*)(vp + base + (size_t)k * 128 + d0);
#pragma unroll
    for (int j = 0; j < 4; ++j) {
      const int d = d0 + j;
      Vt[d * 384 + (k ^ ((d & 7) << 3))] = vv[j];
    }
  }

  bf16x8 qf[3];
#pragma unroll
  for (int t = 0; t < 3; ++t)
    qf[t] = *(const bf16x8*)(qp + base + (size_t)(qbase + t * 16 + lr) * 128 + lg * 8);

  f32x4 acc[3][2]; f32x4 sea[3]; float mrow[3];
#pragma unroll
  for (int t = 0; t < 3; ++t) {
    acc[t][0] = (f32x4)0.f; acc[t][1] = (f32x4)0.f;
    sea[t] = (f32x4)0.f; mrow[t] = -1e30f;
  }
  bf16x8 ones;
#pragma unroll
  for (int i = 0; i < 8; ++i) ones[i] = (__bf16)1.0f;
  const f32x4 zf = (f32x4)0.f;

  __syncthreads();  // V staged; waves now fully independent

  for (int c = 0; c < 12; ++c) {
    const bf16x8 kf0 = *(const bf16x8*)(kp + base + (size_t)(c * 32 + lr) * 128 + lg * 8);
    const bf16x8 kf1 = *(const bf16x8*)(kp + base + (size_t)(c * 32 + 16 + lr) * 128 + lg * 8);
    const bf16x8 vf0 = *(const bf16x8*)&Vt[lr * 384 + ((c * 32 + lg * 8) ^ ((lr & 7) << 3))];
    const bf16x8 vf1 = *(const bf16x8*)&Vt[(16 + lr) * 384 + ((c * 32 + lg * 8) ^ ((lr & 7) << 3))];

#pragma unroll
    for (int t = 0; t < 3; ++t) {
      f32x4 s0 = __builtin_amdgcn_mfma_f32_16x16x32_bf16(qf[t], kf0, zf, 0, 0, 0);
      f32x4 s1 = __builtin_amdgcn_mfma_f32_16x16x32_bf16(qf[t], kf1, zf, 0, 0, 0);
      float cm = fmaxf(fmaxf(fmaxf(s0[0], s0[1]), fmaxf(s0[2], s0[3])),
                       fmaxf(fmaxf(s1[0], s1[1]), fmaxf(s1[2], s1[3])));
      cm = fmaxf(cm, __shfl_xor(cm, 1));
      cm = fmaxf(cm, __shfl_xor(cm, 2));
      cm = fmaxf(cm, __shfl_xor(cm, 4));
      cm = fmaxf(cm, __shfl_xor(cm, 8));
      const float mo = mrow[t];
      const float mn = fmaxf(mo, cm);
      const float corr = __expf(mo - mn);  // chunk 0: exp(-1e30)=0
      mrow[t] = mn;
#pragma unroll
      for (int r = 0; r < 4; ++r) {
        acc[t][0][r] *= corr; acc[t][1][r] *= corr; sea[t][r] *= corr;
      }
#pragma unroll
      for (int r = 0; r < 4; ++r) {
        const float p0 = __expf(s0[r] - mn), p1 = __expf(s1[r] - mn);
        const int q = lg * 4 + r;
        // truncation bias cancels exactly: sea uses the same truncated P
        Pl[wave][(q * 32 + lr) ^ ((q & 7) << 3)] = f2bf_trunc(p0);
        Pl[wave][(q * 32 + 16 + lr) ^ ((q & 7) << 3)] = f2bf_trunc(p1);
      }
      __builtin_amdgcn_sched_barrier(0);  // P-stores before pa-load (rule #18)
      const bf16x8 pa = *(const bf16x8*)&Pl[wave][(lr * 32 + lg * 8) ^ ((lr & 7) << 3)];
      acc[t][0] = __builtin_amdgcn_mfma_f32_16x16x32_bf16(pa, vf0, acc[t][0], 0, 0, 0);
      acc[t][1] = __builtin_amdgcn_mfma_f32_16x16x32_bf16(pa, vf1, acc[t][1], 0, 0, 0);
      sea[t]    = __builtin_amdgcn_mfma_f32_16x16x32_bf16(pa, ones, sea[t], 0, 0, 0);
      __builtin_amdgcn_sched_barrier(0);  // next P-stores after pa-load
    }
  }

#pragma unroll
  for (int t = 0; t < 3; ++t) {
#pragma unroll
    for (int r = 0; r < 4; ++r) {
      const float inv = 1.f / sea[t][r];
      const int row = qbase + t * 16 + lg * 4 + r;
      float* orow = ao + (size_t)(bl * QQ + row) * 128 + h * 32;
      orow[lr]      = acc[t][0][r] * inv;
      orow[16 + lr] = acc[t][1][r] * inv;
    }
  }
}

// ---------------------------------------------------------------------------
// Kernel 3: mean-over-N fused into final projection + bias + skip.
// ---------------------------------------------------------------------------
__global__ __launch_bounds__(256) void proj_skip_mean(
    const float* __restrict__ ao, const float* __restrict__ W,
    const float* __restrict__ bias, const float* __restrict__ skip,
    float* __restrict__ out)
{
  __shared__ float4 Wl[128 * 32];
  __shared__ float4 Xl[32 * 32];
  const int tid = threadIdx.x;
  const float4* W4 = (const float4*)W;
#pragma unroll
  for (int i = 0; i < 16; ++i) Wl[i * 256 + tid] = W4[i * 256 + tid];
  const int tile0 = blockIdx.x * 32;
  const float4* a4 = (const float4*)ao;
#pragma unroll
  for (int i = 0; i < 4; ++i) {
    const int e = i * 256 + tid;          // float4 slot in [32 rows][32]
    const int row = tile0 + (e >> 5);
    const int f4 = e & 31;
    const int bl = row >> 6, w = row & 63;
    const size_t rbase = ((size_t)bl * 384 + w) * 32 + f4;
    float4 s = make_float4(0.f, 0.f, 0.f, 0.f);
#pragma unroll
    for (int n = 0; n < 6; ++n) {
      const float4 vv = a4[rbase + (size_t)n * 64 * 32];
      s.x += vv.x; s.y += vv.y; s.z += vv.z; s.w += vv.w;
    }
    const float inv6 = 1.f / 6.f;
    s.x *= inv6; s.y *= inv6; s.z *= inv6; s.w *= inv6;
    Xl[e] = s;
  }
  __syncthreads();

  const int jg  = tid & 31;
  const int tg4 = tid >> 5;
  float acc[4][4];
#pragma unroll
  for (int a = 0; a < 4; ++a)
#pragma unroll
    for (int c = 0; c < 4; ++c) acc[a][c] = 0.f;

  for (int d4 = 0; d4 < 32; ++d4) {
    float4 wv[4], xv[4];
#pragma unroll
    for (int dd = 0; dd < 4; ++dd) wv[dd] = Wl[(d4 * 4 + dd) * 32 + jg];
#pragma unroll
    for (int tt = 0; tt < 4; ++tt) xv[tt] = Xl[(tg4 * 4 + tt) * 32 + d4];
#pragma unroll
    for (int tt = 0; tt < 4; ++tt) {
      const float4 x = xv[tt];
#define FMA4(xc, wvd)                 \
      acc[tt][0] += (xc) * (wvd).x;   \
      acc[tt][1] += (xc) * (wvd).y;   \
      acc[tt][2] += (xc) * (wvd).z;   \
      acc[tt][3] += (xc) * (wvd).w;
      FMA4(x.x, wv[0]) FMA4(x.y, wv[1]) FMA4(x.z, wv[2]) FMA4(x.w, wv[3])
#undef FMA4
    }
  }

  const float4 bv = ((const float4*)bias)[jg];
  float4* out4 = (float4*)out;
  const float4* sk4 = (const float4*)skip;
#pragma unroll
  for (int tt = 0; tt < 4; ++tt) {
    const int row = tile0 + tg4 * 4 + tt;
    const float4 sk = sk4[(size_t)row * 32 + jg];
    float4 o;
    o.x = acc[tt][0] + bv.x + sk.x;
    o.y = acc[tt][1] + bv.y + sk.y;
    o.z = acc[tt][2] + bv.z + sk.z;
    o.w = acc[tt][3] + bv.w + sk.w;
    out4[(size_t)row * 32 + jg] = o;
  }
}

// ---------------------------------------------------------------------------
extern "C" void kernel_launch(void* const* d_in, const int* in_sizes, int n_in,
                              void* d_out, int out_size, void* d_ws, size_t ws_size,
                              hipStream_t stream)
{
  const float* q     = (const float*)d_in[0];
  const float* k     = (const float*)d_in[1];
  const float* v     = (const float*)d_in[2];
  const float* skip  = (const float*)d_in[3];
  const float* lnq_g = (const float*)d_in[4];
  const float* lnq_b = (const float*)d_in[5];
  const float* lnk_g = (const float*)d_in[6];
  const float* lnk_b = (const float*)d_in[7];
  const float* lnv_g = (const float*)d_in[8];
  const float* lnv_b = (const float*)d_in[9];
  const float* wq = (const float*)d_in[10];
  const float* bq = (const float*)d_in[11];
  const float* wk = (const float*)d_in[12];
  const float* bk = (const float*)d_in[13];
  const float* wv = (const float*)d_in[14];
  const float* bv = (const float*)d_in[15];
  const float* wp = (const float*)d_in[16];
  const float* bp = (const float*)d_in[17];
  float* out = (float*)d_out;

  const size_t PROJ = (size_t)TOK * 128;  // elements
  unsigned short* qp = (unsigned short*)d_ws;
  unsigned short* kp = qp + PROJ;
  unsigned short* vp = kp + PROJ;
  float* ao = (float*)(vp + PROJ);
  unsigned short* wtq = (unsigned short*)(ao + PROJ);
  unsigned short* wtk = wtq + 16384;
  unsigned short* wtv = wtk + 16384;

  transpose_w_kernel<<<64, 256, 0, stream>>>(wq, wk, wv, wtq, wtk, wtv);
  ln_proj_all<<<2304, 256, 0, stream>>>(q, k, v, lnq_g, lnq_b, lnk_g, lnk_b,
                                        lnv_g, lnv_b, wtq, wtk, wtv,
                                        bq, bk, bv, qp, kp, vp);
  attn_mfma_kernel<<<1024, 256, 0, stream>>>(qp, kp, vp, ao);
  proj_skip_mean<<<256, 256, 0, stream>>>(ao, wp, bp, skip, out);
}